// Round 1
// baseline (530.335 us; speedup 1.0000x reference)
//
#include <hip/hip_runtime.h>

#define DIN 128
#define DH  128
#define DOUT 64

// ---------------- CSR build ----------------

__global__ void k_count(const int* __restrict__ dst, int* __restrict__ cnt, int E) {
    int e = blockIdx.x * 256 + threadIdx.x;
    if (e < E) atomicAdd(&cnt[dst[e]], 1);
}

__global__ void k_dinv(const int* __restrict__ cnt, float* __restrict__ dinv, int n) {
    int i = blockIdx.x * 256 + threadIdx.x;
    if (i < n) dinv[i] = rsqrtf((float)(cnt[i] + 1));   // +1 self-loop; always > 0
}

// exclusive scan of cnt -> excl (1024 elems per block), block sums -> bsum
__global__ void k_scan_partial(const int* __restrict__ cnt, int* __restrict__ excl,
                               int* __restrict__ bsum, int n) {
    __shared__ int sd[256];
    int t = threadIdx.x;
    int base = blockIdx.x * 1024 + t * 4;
    int v0 = (base + 0 < n) ? cnt[base + 0] : 0;
    int v1 = (base + 1 < n) ? cnt[base + 1] : 0;
    int v2 = (base + 2 < n) ? cnt[base + 2] : 0;
    int v3 = (base + 3 < n) ? cnt[base + 3] : 0;
    int s = v0 + v1 + v2 + v3;
    sd[t] = s;
    __syncthreads();
    for (int off = 1; off < 256; off <<= 1) {
        int x = (t >= off) ? sd[t - off] : 0;
        __syncthreads();
        sd[t] += x;
        __syncthreads();
    }
    int incl = sd[t];
    if (t == 255) bsum[blockIdx.x] = incl;
    int run = incl - s;
    if (base + 0 < n) excl[base + 0] = run;  run += v0;
    if (base + 1 < n) excl[base + 1] = run;  run += v1;
    if (base + 2 < n) excl[base + 2] = run;  run += v2;
    if (base + 3 < n) excl[base + 3] = run;
}

__global__ void k_scan_bsum(int* __restrict__ bsum, int nb) {
    __shared__ int sd[256];
    int t = threadIdx.x;
    int v = (t < nb) ? bsum[t] : 0;
    sd[t] = v;
    __syncthreads();
    for (int off = 1; off < 256; off <<= 1) {
        int x = (t >= off) ? sd[t - off] : 0;
        __syncthreads();
        sd[t] += x;
        __syncthreads();
    }
    if (t < nb) bsum[t] = sd[t] - v;   // exclusive
}

__global__ void k_finalize(int* __restrict__ rowstart, const int* __restrict__ bsum,
                           int* __restrict__ cursor, int n, int E) {
    int i = blockIdx.x * 256 + threadIdx.x;
    if (i < n) {
        int v = rowstart[i] + bsum[i >> 10];
        rowstart[i] = v;
        cursor[i] = v;
    }
    if (i == 0) rowstart[n] = E;
}

__global__ void k_fill(const int* __restrict__ src, const int* __restrict__ dst,
                       int* __restrict__ cursor, int* __restrict__ adj, int E) {
    int e = blockIdx.x * 256 + threadIdx.x;
    if (e < E) {
        int p = atomicAdd(&cursor[dst[e]], 1);
        adj[p] = src[e];
    }
}

// ---------------- GEMM: S[i][j] = dinv[i] * sum_k A[i][k] * W[k][j] ----------------
// A row stride = 128 (both layers). K = 128. Tile: 32 rows x 64 cols, 256 threads.

__global__ void k_gemm_scaled(const float* __restrict__ A, const float* __restrict__ W,
                              const float* __restrict__ dinv, float* __restrict__ S,
                              int M, int ncols) {
    __shared__ float xs[32 * 132];   // 32 rows x 128 cols, stride 132 (pad: conflict-free a-reads)
    __shared__ float ws[128 * 64];   // 128 k x 64 cols
    int tid = threadIdx.x;
    int row0 = blockIdx.x * 32;
    int j0   = blockIdx.y * 64;

    // stage A tile: 1024 float4
    #pragma unroll
    for (int i = 0; i < 4; i++) {
        int idx = tid + 256 * i;          // 0..1023
        int r = idx >> 5;                 // 0..31
        int kq = idx & 31;                // 0..31 (float4 units)
        float4 val = make_float4(0.f, 0.f, 0.f, 0.f);
        int row = row0 + r;
        if (row < M) val = *(const float4*)(A + (size_t)row * 128 + kq * 4);
        *(float4*)(xs + r * 132 + kq * 4) = val;
    }
    // stage W tile: 2048 float4
    #pragma unroll
    for (int i = 0; i < 8; i++) {
        int idx = tid + 256 * i;          // 0..2047
        int k = idx >> 4;                 // 0..127
        int jq = idx & 15;                // 0..15
        float4 val = *(const float4*)(W + (size_t)k * ncols + j0 + jq * 4);
        *(float4*)(ws + k * 64 + jq * 4) = val;
    }
    __syncthreads();

    int tx = tid & 15;        // 4 cols each: j = j0 + tx*4 ..
    int ty = tid >> 4;        // 2 rows each: m = ty*2 + r
    float acc[2][4] = {};
    #pragma unroll 8
    for (int k = 0; k < 128; k++) {
        float4 b = *(const float4*)(ws + k * 64 + tx * 4);
        float a0 = xs[(ty * 2 + 0) * 132 + k];
        float a1 = xs[(ty * 2 + 1) * 132 + k];
        acc[0][0] += a0 * b.x; acc[0][1] += a0 * b.y; acc[0][2] += a0 * b.z; acc[0][3] += a0 * b.w;
        acc[1][0] += a1 * b.x; acc[1][1] += a1 * b.y; acc[1][2] += a1 * b.z; acc[1][3] += a1 * b.w;
    }

    #pragma unroll
    for (int r = 0; r < 2; r++) {
        int row = row0 + ty * 2 + r;
        if (row < M) {
            float dv = dinv[row];
            float4 o;
            o.x = dv * acc[r][0]; o.y = dv * acc[r][1];
            o.z = dv * acc[r][2]; o.w = dv * acc[r][3];
            *(float4*)(S + (size_t)row * ncols + j0 + tx * 4) = o;
        }
    }
}

// ---------------- Aggregation: out[i] = act(dinv[i]*(S[i] + sum_in S[src]) + b) ----------------
// one wave (64 lanes) per node; 4 nodes per 256-thread block

template <int D, bool RELU>
__global__ void k_aggregate(const float* __restrict__ S, const int* __restrict__ rowstart,
                            const int* __restrict__ adj, const float* __restrict__ dinv,
                            const float* __restrict__ bias, float* __restrict__ out, int n) {
    int wave = threadIdx.x >> 6;
    int lane = threadIdx.x & 63;
    int node = blockIdx.x * 4 + wave;
    if (node >= n) return;
    int start = rowstart[node];
    int end   = rowstart[node + 1];

    if (D == 128) {
        float2 acc  = *(const float2*)(S + (size_t)node * 128 + lane * 2);  // self-loop term
        float2 acc2 = make_float2(0.f, 0.f);
        int t = start;
        for (; t + 1 < end; t += 2) {
            int j0 = adj[t], j1 = adj[t + 1];
            float2 m0 = *(const float2*)(S + (size_t)j0 * 128 + lane * 2);
            float2 m1 = *(const float2*)(S + (size_t)j1 * 128 + lane * 2);
            acc.x  += m0.x; acc.y  += m0.y;
            acc2.x += m1.x; acc2.y += m1.y;
        }
        if (t < end) {
            int j = adj[t];
            float2 m = *(const float2*)(S + (size_t)j * 128 + lane * 2);
            acc.x += m.x; acc.y += m.y;
        }
        float dv = dinv[node];
        float2 bb = *(const float2*)(bias + lane * 2);
        float ox = dv * (acc.x + acc2.x) + bb.x;
        float oy = dv * (acc.y + acc2.y) + bb.y;
        if (RELU) { ox = fmaxf(ox, 0.f); oy = fmaxf(oy, 0.f); }
        *(float2*)(out + (size_t)node * 128 + lane * 2) = make_float2(ox, oy);
    } else {
        float acc  = S[(size_t)node * 64 + lane];
        float acc2 = 0.f;
        int t = start;
        for (; t + 1 < end; t += 2) {
            int j0 = adj[t], j1 = adj[t + 1];
            acc  += S[(size_t)j0 * 64 + lane];
            acc2 += S[(size_t)j1 * 64 + lane];
        }
        if (t < end) acc += S[(size_t)adj[t] * 64 + lane];
        float o = dinv[node] * (acc + acc2) + bias[lane];
        if (RELU) o = fmaxf(o, 0.f);
        out[(size_t)node * 64 + lane] = o;
    }
}

// ---------------- launch ----------------

extern "C" void kernel_launch(void* const* d_in, const int* in_sizes, int n_in,
                              void* d_out, int out_size, void* d_ws, size_t ws_size,
                              hipStream_t stream) {
    const float* x  = (const float*)d_in[0];
    const int*   ei = (const int*)d_in[1];
    const float* W1 = (const float*)d_in[2];
    const float* b1 = (const float*)d_in[3];
    const float* W2 = (const float*)d_in[4];
    const float* b2 = (const float*)d_in[5];
    float* out = (float*)d_out;

    int N = in_sizes[0] / DIN;
    int E = in_sizes[1] / 2;
    const int* esrc = ei;
    const int* edst = ei + E;

    char* wsb = (char*)d_ws;
    size_t off = 0;
    auto alloc = [&](size_t bytes) {
        void* p = wsb + off;
        off = (off + bytes + 255) & ~(size_t)255;
        return p;
    };
    float* S        = (float*)alloc((size_t)N * 128 * 4);   // S1, reused as S2
    float* H1       = (float*)alloc((size_t)N * 128 * 4);
    float* dinv     = (float*)alloc((size_t)N * 4);
    int*   cnt      = (int*)alloc((size_t)N * 4);
    int*   rowstart = (int*)alloc((size_t)(N + 1) * 4);
    int*   cursor   = (int*)alloc((size_t)N * 4);
    int*   adj      = (int*)alloc((size_t)E * 4);
    int*   bsum     = (int*)alloc(1024 * 4);

    int eb = (E + 255) / 256;
    int nb = (N + 255) / 256;
    int sb = (N + 1023) / 1024;   // 98 for N=100000, must be <= 256

    hipMemsetAsync(cnt, 0, (size_t)N * 4, stream);
    k_count<<<eb, 256, 0, stream>>>(edst, cnt, E);
    k_dinv<<<nb, 256, 0, stream>>>(cnt, dinv, N);
    k_scan_partial<<<sb, 256, 0, stream>>>(cnt, rowstart, bsum, N);
    k_scan_bsum<<<1, 256, 0, stream>>>(bsum, sb);
    k_finalize<<<nb, 256, 0, stream>>>(rowstart, bsum, cursor, N, E);
    k_fill<<<eb, 256, 0, stream>>>(esrc, edst, cursor, adj, E);

    // layer 1: S1 = dinv .* (x @ W1);  H1 = relu(dinv .* (S1 self+neighbors) + b1)
    dim3 g1((N + 31) / 32, DH / 64);
    k_gemm_scaled<<<g1, 256, 0, stream>>>(x, W1, dinv, S, N, DH);
    int ab = (N + 3) / 4;
    k_aggregate<128, true><<<ab, 256, 0, stream>>>(S, rowstart, adj, dinv, b1, H1, N);

    // layer 2: S2 = dinv .* (H1 @ W2);  out = dinv .* (S2 self+neighbors) + b2
    dim3 g2((N + 31) / 32, DOUT / 64);
    k_gemm_scaled<<<g2, 256, 0, stream>>>(H1, W2, dinv, S, N, DOUT);
    k_aggregate<64, false><<<ab, 256, 0, stream>>>(S, rowstart, adj, dinv, b2, out, N);
}

// Round 2
// 472.642 us; speedup vs baseline: 1.1221x; 1.1221x over previous
//
#include <hip/hip_runtime.h>

#define DIN 128
#define DH  128
#define DOUT 64

// ---------------- CSR build ----------------

__global__ void k_count(const int* __restrict__ dst, int* __restrict__ cnt, int E) {
    int e = blockIdx.x * 256 + threadIdx.x;
    if (e < E) atomicAdd(&cnt[dst[e]], 1);
}

__global__ void k_dinv(const int* __restrict__ cnt, float* __restrict__ dinv, int n) {
    int i = blockIdx.x * 256 + threadIdx.x;
    if (i < n) dinv[i] = rsqrtf((float)(cnt[i] + 1));   // +1 self-loop; always > 0
}

// exclusive scan of cnt -> excl (1024 elems per block), block sums -> bsum
__global__ void k_scan_partial(const int* __restrict__ cnt, int* __restrict__ excl,
                               int* __restrict__ bsum, int n) {
    __shared__ int sd[256];
    int t = threadIdx.x;
    int base = blockIdx.x * 1024 + t * 4;
    int v0 = (base + 0 < n) ? cnt[base + 0] : 0;
    int v1 = (base + 1 < n) ? cnt[base + 1] : 0;
    int v2 = (base + 2 < n) ? cnt[base + 2] : 0;
    int v3 = (base + 3 < n) ? cnt[base + 3] : 0;
    int s = v0 + v1 + v2 + v3;
    sd[t] = s;
    __syncthreads();
    for (int off = 1; off < 256; off <<= 1) {
        int x = (t >= off) ? sd[t - off] : 0;
        __syncthreads();
        sd[t] += x;
        __syncthreads();
    }
    int incl = sd[t];
    if (t == 255) bsum[blockIdx.x] = incl;
    int run = incl - s;
    if (base + 0 < n) excl[base + 0] = run;  run += v0;
    if (base + 1 < n) excl[base + 1] = run;  run += v1;
    if (base + 2 < n) excl[base + 2] = run;  run += v2;
    if (base + 3 < n) excl[base + 3] = run;
}

__global__ void k_scan_bsum(int* __restrict__ bsum, int nb) {
    __shared__ int sd[256];
    int t = threadIdx.x;
    int v = (t < nb) ? bsum[t] : 0;
    sd[t] = v;
    __syncthreads();
    for (int off = 1; off < 256; off <<= 1) {
        int x = (t >= off) ? sd[t - off] : 0;
        __syncthreads();
        sd[t] += x;
        __syncthreads();
    }
    if (t < nb) bsum[t] = sd[t] - v;   // exclusive
}

__global__ void k_finalize(int* __restrict__ rowstart, const int* __restrict__ bsum,
                           int* __restrict__ cursor, int n, int E) {
    int i = blockIdx.x * 256 + threadIdx.x;
    if (i < n) {
        int v = rowstart[i] + bsum[i >> 10];
        rowstart[i] = v;
        cursor[i] = v;
    }
    if (i == 0) rowstart[n] = E;
}

__global__ void k_fill(const int* __restrict__ src, const int* __restrict__ dst,
                       int* __restrict__ cursor, int* __restrict__ adj, int E) {
    int e = blockIdx.x * 256 + threadIdx.x;
    if (e < E) {
        int p = atomicAdd(&cursor[dst[e]], 1);
        adj[p] = src[e];
    }
}

// ---------------- GEMM: S[i][j] = dinv[i] * sum_k A[i][k] * W[k][j] ----------------

__global__ void k_gemm_scaled(const float* __restrict__ A, const float* __restrict__ W,
                              const float* __restrict__ dinv, float* __restrict__ S,
                              int M, int ncols) {
    __shared__ float xs[32 * 132];
    __shared__ float ws[128 * 64];
    int tid = threadIdx.x;
    int row0 = blockIdx.x * 32;
    int j0   = blockIdx.y * 64;

    #pragma unroll
    for (int i = 0; i < 4; i++) {
        int idx = tid + 256 * i;
        int r = idx >> 5;
        int kq = idx & 31;
        float4 val = make_float4(0.f, 0.f, 0.f, 0.f);
        int row = row0 + r;
        if (row < M) val = *(const float4*)(A + (size_t)row * 128 + kq * 4);
        *(float4*)(xs + r * 132 + kq * 4) = val;
    }
    #pragma unroll
    for (int i = 0; i < 8; i++) {
        int idx = tid + 256 * i;
        int k = idx >> 4;
        int jq = idx & 15;
        float4 val = *(const float4*)(W + (size_t)k * ncols + j0 + jq * 4);
        *(float4*)(ws + k * 64 + jq * 4) = val;
    }
    __syncthreads();

    int tx = tid & 15;
    int ty = tid >> 4;
    float acc[2][4] = {};
    #pragma unroll 8
    for (int k = 0; k < 128; k++) {
        float4 b = *(const float4*)(ws + k * 64 + tx * 4);
        float a0 = xs[(ty * 2 + 0) * 132 + k];
        float a1 = xs[(ty * 2 + 1) * 132 + k];
        acc[0][0] += a0 * b.x; acc[0][1] += a0 * b.y; acc[0][2] += a0 * b.z; acc[0][3] += a0 * b.w;
        acc[1][0] += a1 * b.x; acc[1][1] += a1 * b.y; acc[1][2] += a1 * b.z; acc[1][3] += a1 * b.w;
    }

    #pragma unroll
    for (int r = 0; r < 2; r++) {
        int row = row0 + ty * 2 + r;
        if (row < M) {
            float dv = dinv[row];
            float4 o;
            o.x = dv * acc[r][0]; o.y = dv * acc[r][1];
            o.z = dv * acc[r][2]; o.w = dv * acc[r][3];
            *(float4*)(S + (size_t)row * ncols + j0 + tx * 4) = o;
        }
    }
}

// ---------------- Aggregation v2: packed multi-edge gathers ----------------
// out[i] = act(dinv[i]*(S[i] + sum_in S[src]) + b)
// D=128: one float4 load (64 lanes x 16B) covers 2 rows (32 lanes x 16B = 512B each).
// D=64 : one float4 load covers 4 rows (16 lanes x 16B = 256B each).

template <bool RELU>
__global__ void k_agg128(const float* __restrict__ S, const int* __restrict__ rowstart,
                         const int* __restrict__ adj, const float* __restrict__ dinv,
                         const float* __restrict__ bias, float* __restrict__ out, int n) {
    int wave = threadIdx.x >> 6;
    int lane = threadIdx.x & 63;
    int node = blockIdx.x * 4 + wave;
    if (node >= n) return;
    int start = rowstart[node];
    int end   = rowstart[node + 1];
    int half = lane >> 5;      // which edge of a pair
    int fo   = lane & 31;      // float4 slot within the 128-float row

    const float4* S4 = (const float4*)S;
    float4 a0 = {0,0,0,0}, a1 = {0,0,0,0}, a2 = {0,0,0,0}, a3 = {0,0,0,0};

    while (start < end) {
        int cnt = end - start;
        if (cnt > 64) cnt = 64;
        int nb = adj[start + (lane < cnt ? lane : cnt - 1)];
        int t = 0;
        for (; t + 8 <= cnt; t += 8) {                 // 8 edges, 4 loads in flight
            int jA = __shfl(nb, t + 0 + half);
            int jB = __shfl(nb, t + 2 + half);
            int jC = __shfl(nb, t + 4 + half);
            int jD = __shfl(nb, t + 6 + half);
            float4 mA = S4[(size_t)jA * 32 + fo];
            float4 mB = S4[(size_t)jB * 32 + fo];
            float4 mC = S4[(size_t)jC * 32 + fo];
            float4 mD = S4[(size_t)jD * 32 + fo];
            a0.x += mA.x; a0.y += mA.y; a0.z += mA.z; a0.w += mA.w;
            a1.x += mB.x; a1.y += mB.y; a1.z += mB.z; a1.w += mB.w;
            a2.x += mC.x; a2.y += mC.y; a2.z += mC.z; a2.w += mC.w;
            a3.x += mD.x; a3.y += mD.y; a3.z += mD.z; a3.w += mD.w;
        }
        for (; t + 2 <= cnt; t += 2) {                 // pair tail
            int j = __shfl(nb, t + half);
            float4 m = S4[(size_t)j * 32 + fo];
            a0.x += m.x; a0.y += m.y; a0.z += m.z; a0.w += m.w;
        }
        if (t < cnt) {                                 // odd final edge: half-0 lanes only
            int j = __shfl(nb, t);
            float4 m = S4[(size_t)j * 32 + fo];
            if (half == 0) { a1.x += m.x; a1.y += m.y; a1.z += m.z; a1.w += m.w; }
        }
        start += 64;
    }

    float4 acc;
    acc.x = (a0.x + a1.x) + (a2.x + a3.x);
    acc.y = (a0.y + a1.y) + (a2.y + a3.y);
    acc.z = (a0.z + a1.z) + (a2.z + a3.z);
    acc.w = (a0.w + a1.w) + (a2.w + a3.w);
    acc.x += __shfl_xor(acc.x, 32);
    acc.y += __shfl_xor(acc.y, 32);
    acc.z += __shfl_xor(acc.z, 32);
    acc.w += __shfl_xor(acc.w, 32);

    float4 self = S4[(size_t)node * 32 + fo];
    float dv = dinv[node];
    float4 bb = ((const float4*)bias)[fo];
    float4 o;
    o.x = dv * (acc.x + self.x) + bb.x;
    o.y = dv * (acc.y + self.y) + bb.y;
    o.z = dv * (acc.z + self.z) + bb.z;
    o.w = dv * (acc.w + self.w) + bb.w;
    if (RELU) {
        o.x = fmaxf(o.x, 0.f); o.y = fmaxf(o.y, 0.f);
        o.z = fmaxf(o.z, 0.f); o.w = fmaxf(o.w, 0.f);
    }
    if (half == 0) ((float4*)out)[(size_t)node * 32 + fo] = o;
}

__global__ void k_agg64(const float* __restrict__ S, const int* __restrict__ rowstart,
                        const int* __restrict__ adj, const float* __restrict__ dinv,
                        const float* __restrict__ bias, float* __restrict__ out, int n) {
    int wave = threadIdx.x >> 6;
    int lane = threadIdx.x & 63;
    int node = blockIdx.x * 4 + wave;
    if (node >= n) return;
    int start = rowstart[node];
    int end   = rowstart[node + 1];
    int q  = lane >> 4;        // which edge of a quad
    int fo = lane & 15;        // float4 slot within the 64-float row

    const float4* S4 = (const float4*)S;
    float4 a0 = {0,0,0,0}, a1 = {0,0,0,0}, a2 = {0,0,0,0}, a3 = {0,0,0,0};

    while (start < end) {
        int cnt = end - start;
        if (cnt > 64) cnt = 64;
        int nb = adj[start + (lane < cnt ? lane : cnt - 1)];
        int t = 0;
        for (; t + 16 <= cnt; t += 16) {               // 16 edges, 4 loads in flight
            int jA = __shfl(nb, t + 0  + q);
            int jB = __shfl(nb, t + 4  + q);
            int jC = __shfl(nb, t + 8  + q);
            int jD = __shfl(nb, t + 12 + q);
            float4 mA = S4[(size_t)jA * 16 + fo];
            float4 mB = S4[(size_t)jB * 16 + fo];
            float4 mC = S4[(size_t)jC * 16 + fo];
            float4 mD = S4[(size_t)jD * 16 + fo];
            a0.x += mA.x; a0.y += mA.y; a0.z += mA.z; a0.w += mA.w;
            a1.x += mB.x; a1.y += mB.y; a1.z += mB.z; a1.w += mB.w;
            a2.x += mC.x; a2.y += mC.y; a2.z += mC.z; a2.w += mC.w;
            a3.x += mD.x; a3.y += mD.y; a3.z += mD.z; a3.w += mD.w;
        }
        for (; t + 4 <= cnt; t += 4) {                 // quad tail
            int j = __shfl(nb, t + q);
            float4 m = S4[(size_t)j * 16 + fo];
            a0.x += m.x; a0.y += m.y; a0.z += m.z; a0.w += m.w;
        }
        if (t < cnt) {                                 // 1..3 leftover edges
            int i1 = t + q;
            int j = __shfl(nb, i1 < cnt ? i1 : cnt - 1);
            float4 m = S4[(size_t)j * 16 + fo];
            if (i1 < cnt) { a1.x += m.x; a1.y += m.y; a1.z += m.z; a1.w += m.w; }
        }
        start += 64;
    }

    float4 acc;
    acc.x = (a0.x + a1.x) + (a2.x + a3.x);
    acc.y = (a0.y + a1.y) + (a2.y + a3.y);
    acc.z = (a0.z + a1.z) + (a2.z + a3.z);
    acc.w = (a0.w + a1.w) + (a2.w + a3.w);
    acc.x += __shfl_xor(acc.x, 16);
    acc.y += __shfl_xor(acc.y, 16);
    acc.z += __shfl_xor(acc.z, 16);
    acc.w += __shfl_xor(acc.w, 16);
    acc.x += __shfl_xor(acc.x, 32);
    acc.y += __shfl_xor(acc.y, 32);
    acc.z += __shfl_xor(acc.z, 32);
    acc.w += __shfl_xor(acc.w, 32);

    float4 self = S4[(size_t)node * 16 + fo];
    float dv = dinv[node];
    float4 bb = ((const float4*)bias)[fo];
    float4 o;
    o.x = dv * (acc.x + self.x) + bb.x;
    o.y = dv * (acc.y + self.y) + bb.y;
    o.z = dv * (acc.z + self.z) + bb.z;
    o.w = dv * (acc.w + self.w) + bb.w;
    if (lane < 16) ((float4*)out)[(size_t)node * 16 + fo] = o;
}

// ---------------- launch ----------------

extern "C" void kernel_launch(void* const* d_in, const int* in_sizes, int n_in,
                              void* d_out, int out_size, void* d_ws, size_t ws_size,
                              hipStream_t stream) {
    const float* x  = (const float*)d_in[0];
    const int*   ei = (const int*)d_in[1];
    const float* W1 = (const float*)d_in[2];
    const float* b1 = (const float*)d_in[3];
    const float* W2 = (const float*)d_in[4];
    const float* b2 = (const float*)d_in[5];
    float* out = (float*)d_out;

    int N = in_sizes[0] / DIN;
    int E = in_sizes[1] / 2;
    const int* esrc = ei;
    const int* edst = ei + E;

    char* wsb = (char*)d_ws;
    size_t off = 0;
    auto alloc = [&](size_t bytes) {
        void* p = wsb + off;
        off = (off + bytes + 255) & ~(size_t)255;
        return p;
    };
    float* S        = (float*)alloc((size_t)N * 128 * 4);
    float* H1       = (float*)alloc((size_t)N * 128 * 4);
    float* dinv     = (float*)alloc((size_t)N * 4);
    int*   cnt      = (int*)alloc((size_t)N * 4);
    int*   rowstart = (int*)alloc((size_t)(N + 1) * 4);
    int*   cursor   = (int*)alloc((size_t)N * 4);
    int*   adj      = (int*)alloc((size_t)E * 4);
    int*   bsum     = (int*)alloc(1024 * 4);

    int eb = (E + 255) / 256;
    int nb = (N + 255) / 256;
    int sb = (N + 1023) / 1024;

    hipMemsetAsync(cnt, 0, (size_t)N * 4, stream);
    k_count<<<eb, 256, 0, stream>>>(edst, cnt, E);
    k_dinv<<<nb, 256, 0, stream>>>(cnt, dinv, N);
    k_scan_partial<<<sb, 256, 0, stream>>>(cnt, rowstart, bsum, N);
    k_scan_bsum<<<1, 256, 0, stream>>>(bsum, sb);
    k_finalize<<<nb, 256, 0, stream>>>(rowstart, bsum, cursor, N, E);
    k_fill<<<eb, 256, 0, stream>>>(esrc, edst, cursor, adj, E);

    dim3 g1((N + 31) / 32, DH / 64);
    k_gemm_scaled<<<g1, 256, 0, stream>>>(x, W1, dinv, S, N, DH);
    int ab = (N + 3) / 4;
    k_agg128<true><<<ab, 256, 0, stream>>>(S, rowstart, adj, dinv, b1, H1, N);

    dim3 g2((N + 31) / 32, DOUT / 64);
    k_gemm_scaled<<<g2, 256, 0, stream>>>(H1, W2, dinv, S, N, DOUT);
    k_agg64<<<ab, 256, 0, stream>>>(S, rowstart, adj, dinv, b2, out, N);
}

// Round 3
// 369.528 us; speedup vs baseline: 1.4352x; 1.2790x over previous
//
#include <hip/hip_runtime.h>

#define DIN 128
#define DH  128
#define DOUT 64

// ---------------- CSR build v2: one atomic pass (rank), atomic-free placement ----------------

// rank[e] = position of edge e within its dst row; cnt accumulates in-degree.
// cnt is padded (stride `pad` ints) to put each counter on its own cacheline.
__global__ void k_count_rank(const int* __restrict__ dst, int* __restrict__ cnt,
                             int* __restrict__ rank, int E, int pad) {
    int e = blockIdx.x * 256 + threadIdx.x;
    if (e < E) rank[e] = atomicAdd(&cnt[dst[e] * pad], 1);
}

__global__ void k_dinv(const int* __restrict__ cnt, float* __restrict__ dinv, int n, int pad) {
    int i = blockIdx.x * 256 + threadIdx.x;
    if (i < n) dinv[i] = rsqrtf((float)(cnt[i * pad] + 1));   // +1 self-loop; always > 0
}

// exclusive scan of cnt (padded) -> excl (1024 elems per block), block sums -> bsum
__global__ void k_scan_partial(const int* __restrict__ cnt, int* __restrict__ excl,
                               int* __restrict__ bsum, int n, int pad) {
    __shared__ int sd[256];
    int t = threadIdx.x;
    int base = blockIdx.x * 1024 + t * 4;
    int v0 = (base + 0 < n) ? cnt[(base + 0) * pad] : 0;
    int v1 = (base + 1 < n) ? cnt[(base + 1) * pad] : 0;
    int v2 = (base + 2 < n) ? cnt[(base + 2) * pad] : 0;
    int v3 = (base + 3 < n) ? cnt[(base + 3) * pad] : 0;
    int s = v0 + v1 + v2 + v3;
    sd[t] = s;
    __syncthreads();
    for (int off = 1; off < 256; off <<= 1) {
        int x = (t >= off) ? sd[t - off] : 0;
        __syncthreads();
        sd[t] += x;
        __syncthreads();
    }
    int incl = sd[t];
    if (t == 255) bsum[blockIdx.x] = incl;
    int run = incl - s;
    if (base + 0 < n) excl[base + 0] = run;  run += v0;
    if (base + 1 < n) excl[base + 1] = run;  run += v1;
    if (base + 2 < n) excl[base + 2] = run;  run += v2;
    if (base + 3 < n) excl[base + 3] = run;
}

__global__ void k_scan_bsum(int* __restrict__ bsum, int nb) {
    __shared__ int sd[256];
    int t = threadIdx.x;
    int v = (t < nb) ? bsum[t] : 0;
    sd[t] = v;
    __syncthreads();
    for (int off = 1; off < 256; off <<= 1) {
        int x = (t >= off) ? sd[t - off] : 0;
        __syncthreads();
        sd[t] += x;
        __syncthreads();
    }
    if (t < nb) bsum[t] = sd[t] - v;   // exclusive
}

__global__ void k_finalize(int* __restrict__ rowstart, const int* __restrict__ bsum,
                           int n, int E) {
    int i = blockIdx.x * 256 + threadIdx.x;
    if (i < n) rowstart[i] += bsum[i >> 10];
    if (i == 0) rowstart[n] = E;
}

// placement: no atomics — position = rowstart[dst] + rank
__global__ void k_fill2(const int* __restrict__ src, const int* __restrict__ dst,
                        const int* __restrict__ rank, const int* __restrict__ rowstart,
                        int* __restrict__ adj, int E) {
    int e = blockIdx.x * 256 + threadIdx.x;
    if (e < E) adj[rowstart[dst[e]] + rank[e]] = src[e];
}

// ---------------- GEMM: S[i][j] = dinv[i] * sum_k A[i][k] * W[k][j] ----------------

__global__ void k_gemm_scaled(const float* __restrict__ A, const float* __restrict__ W,
                              const float* __restrict__ dinv, float* __restrict__ S,
                              int M, int ncols) {
    __shared__ float xs[32 * 132];
    __shared__ float ws[128 * 64];
    int tid = threadIdx.x;
    int row0 = blockIdx.x * 32;
    int j0   = blockIdx.y * 64;

    #pragma unroll
    for (int i = 0; i < 4; i++) {
        int idx = tid + 256 * i;
        int r = idx >> 5;
        int kq = idx & 31;
        float4 val = make_float4(0.f, 0.f, 0.f, 0.f);
        int row = row0 + r;
        if (row < M) val = *(const float4*)(A + (size_t)row * 128 + kq * 4);
        *(float4*)(xs + r * 132 + kq * 4) = val;
    }
    #pragma unroll
    for (int i = 0; i < 8; i++) {
        int idx = tid + 256 * i;
        int k = idx >> 4;
        int jq = idx & 15;
        float4 val = *(const float4*)(W + (size_t)k * ncols + j0 + jq * 4);
        *(float4*)(ws + k * 64 + jq * 4) = val;
    }
    __syncthreads();

    int tx = tid & 15;
    int ty = tid >> 4;
    float acc[2][4] = {};
    #pragma unroll 8
    for (int k = 0; k < 128; k++) {
        float4 b = *(const float4*)(ws + k * 64 + tx * 4);
        float a0 = xs[(ty * 2 + 0) * 132 + k];
        float a1 = xs[(ty * 2 + 1) * 132 + k];
        acc[0][0] += a0 * b.x; acc[0][1] += a0 * b.y; acc[0][2] += a0 * b.z; acc[0][3] += a0 * b.w;
        acc[1][0] += a1 * b.x; acc[1][1] += a1 * b.y; acc[1][2] += a1 * b.z; acc[1][3] += a1 * b.w;
    }

    #pragma unroll
    for (int r = 0; r < 2; r++) {
        int row = row0 + ty * 2 + r;
        if (row < M) {
            float dv = dinv[row];
            float4 o;
            o.x = dv * acc[r][0]; o.y = dv * acc[r][1];
            o.z = dv * acc[r][2]; o.w = dv * acc[r][3];
            *(float4*)(S + (size_t)row * ncols + j0 + tx * 4) = o;
        }
    }
}

// ---------------- Aggregation: packed multi-edge gathers ----------------

template <bool RELU>
__global__ void k_agg128(const float* __restrict__ S, const int* __restrict__ rowstart,
                         const int* __restrict__ adj, const float* __restrict__ dinv,
                         const float* __restrict__ bias, float* __restrict__ out, int n) {
    int wave = threadIdx.x >> 6;
    int lane = threadIdx.x & 63;
    int node = blockIdx.x * 4 + wave;
    if (node >= n) return;
    int start = rowstart[node];
    int end   = rowstart[node + 1];
    int half = lane >> 5;
    int fo   = lane & 31;

    const float4* S4 = (const float4*)S;
    float4 a0 = {0,0,0,0}, a1 = {0,0,0,0}, a2 = {0,0,0,0}, a3 = {0,0,0,0};

    while (start < end) {
        int cnt = end - start;
        if (cnt > 64) cnt = 64;
        int nb = adj[start + (lane < cnt ? lane : cnt - 1)];
        int t = 0;
        for (; t + 8 <= cnt; t += 8) {
            int jA = __shfl(nb, t + 0 + half);
            int jB = __shfl(nb, t + 2 + half);
            int jC = __shfl(nb, t + 4 + half);
            int jD = __shfl(nb, t + 6 + half);
            float4 mA = S4[(size_t)jA * 32 + fo];
            float4 mB = S4[(size_t)jB * 32 + fo];
            float4 mC = S4[(size_t)jC * 32 + fo];
            float4 mD = S4[(size_t)jD * 32 + fo];
            a0.x += mA.x; a0.y += mA.y; a0.z += mA.z; a0.w += mA.w;
            a1.x += mB.x; a1.y += mB.y; a1.z += mB.z; a1.w += mB.w;
            a2.x += mC.x; a2.y += mC.y; a2.z += mC.z; a2.w += mC.w;
            a3.x += mD.x; a3.y += mD.y; a3.z += mD.z; a3.w += mD.w;
        }
        for (; t + 2 <= cnt; t += 2) {
            int j = __shfl(nb, t + half);
            float4 m = S4[(size_t)j * 32 + fo];
            a0.x += m.x; a0.y += m.y; a0.z += m.z; a0.w += m.w;
        }
        if (t < cnt) {
            int j = __shfl(nb, t);
            float4 m = S4[(size_t)j * 32 + fo];
            if (half == 0) { a1.x += m.x; a1.y += m.y; a1.z += m.z; a1.w += m.w; }
        }
        start += 64;
    }

    float4 acc;
    acc.x = (a0.x + a1.x) + (a2.x + a3.x);
    acc.y = (a0.y + a1.y) + (a2.y + a3.y);
    acc.z = (a0.z + a1.z) + (a2.z + a3.z);
    acc.w = (a0.w + a1.w) + (a2.w + a3.w);
    acc.x += __shfl_xor(acc.x, 32);
    acc.y += __shfl_xor(acc.y, 32);
    acc.z += __shfl_xor(acc.z, 32);
    acc.w += __shfl_xor(acc.w, 32);

    float4 self = S4[(size_t)node * 32 + fo];
    float dv = dinv[node];
    float4 bb = ((const float4*)bias)[fo];
    float4 o;
    o.x = dv * (acc.x + self.x) + bb.x;
    o.y = dv * (acc.y + self.y) + bb.y;
    o.z = dv * (acc.z + self.z) + bb.z;
    o.w = dv * (acc.w + self.w) + bb.w;
    if (RELU) {
        o.x = fmaxf(o.x, 0.f); o.y = fmaxf(o.y, 0.f);
        o.z = fmaxf(o.z, 0.f); o.w = fmaxf(o.w, 0.f);
    }
    if (half == 0) ((float4*)out)[(size_t)node * 32 + fo] = o;
}

__global__ void k_agg64(const float* __restrict__ S, const int* __restrict__ rowstart,
                        const int* __restrict__ adj, const float* __restrict__ dinv,
                        const float* __restrict__ bias, float* __restrict__ out, int n) {
    int wave = threadIdx.x >> 6;
    int lane = threadIdx.x & 63;
    int node = blockIdx.x * 4 + wave;
    if (node >= n) return;
    int start = rowstart[node];
    int end   = rowstart[node + 1];
    int q  = lane >> 4;
    int fo = lane & 15;

    const float4* S4 = (const float4*)S;
    float4 a0 = {0,0,0,0}, a1 = {0,0,0,0}, a2 = {0,0,0,0}, a3 = {0,0,0,0};

    while (start < end) {
        int cnt = end - start;
        if (cnt > 64) cnt = 64;
        int nb = adj[start + (lane < cnt ? lane : cnt - 1)];
        int t = 0;
        for (; t + 16 <= cnt; t += 16) {
            int jA = __shfl(nb, t + 0  + q);
            int jB = __shfl(nb, t + 4  + q);
            int jC = __shfl(nb, t + 8  + q);
            int jD = __shfl(nb, t + 12 + q);
            float4 mA = S4[(size_t)jA * 16 + fo];
            float4 mB = S4[(size_t)jB * 16 + fo];
            float4 mC = S4[(size_t)jC * 16 + fo];
            float4 mD = S4[(size_t)jD * 16 + fo];
            a0.x += mA.x; a0.y += mA.y; a0.z += mA.z; a0.w += mA.w;
            a1.x += mB.x; a1.y += mB.y; a1.z += mB.z; a1.w += mB.w;
            a2.x += mC.x; a2.y += mC.y; a2.z += mC.z; a2.w += mC.w;
            a3.x += mD.x; a3.y += mD.y; a3.z += mD.z; a3.w += mD.w;
        }
        for (; t + 4 <= cnt; t += 4) {
            int j = __shfl(nb, t + q);
            float4 m = S4[(size_t)j * 16 + fo];
            a0.x += m.x; a0.y += m.y; a0.z += m.z; a0.w += m.w;
        }
        if (t < cnt) {
            int i1 = t + q;
            int j = __shfl(nb, i1 < cnt ? i1 : cnt - 1);
            float4 m = S4[(size_t)j * 16 + fo];
            if (i1 < cnt) { a1.x += m.x; a1.y += m.y; a1.z += m.z; a1.w += m.w; }
        }
        start += 64;
    }

    float4 acc;
    acc.x = (a0.x + a1.x) + (a2.x + a3.x);
    acc.y = (a0.y + a1.y) + (a2.y + a3.y);
    acc.z = (a0.z + a1.z) + (a2.z + a3.z);
    acc.w = (a0.w + a1.w) + (a2.w + a3.w);
    acc.x += __shfl_xor(acc.x, 16);
    acc.y += __shfl_xor(acc.y, 16);
    acc.z += __shfl_xor(acc.z, 16);
    acc.w += __shfl_xor(acc.w, 16);
    acc.x += __shfl_xor(acc.x, 32);
    acc.y += __shfl_xor(acc.y, 32);
    acc.z += __shfl_xor(acc.z, 32);
    acc.w += __shfl_xor(acc.w, 32);

    float4 self = S4[(size_t)node * 16 + fo];
    float dv = dinv[node];
    float4 bb = ((const float4*)bias)[fo];
    float4 o;
    o.x = dv * (acc.x + self.x) + bb.x;
    o.y = dv * (acc.y + self.y) + bb.y;
    o.z = dv * (acc.z + self.z) + bb.z;
    o.w = dv * (acc.w + self.w) + bb.w;
    if (lane < 16) ((float4*)out)[(size_t)node * 16 + fo] = o;
}

// ---------------- launch ----------------

extern "C" void kernel_launch(void* const* d_in, const int* in_sizes, int n_in,
                              void* d_out, int out_size, void* d_ws, size_t ws_size,
                              hipStream_t stream) {
    const float* x  = (const float*)d_in[0];
    const int*   ei = (const int*)d_in[1];
    const float* W1 = (const float*)d_in[2];
    const float* b1 = (const float*)d_in[3];
    const float* W2 = (const float*)d_in[4];
    const float* b2 = (const float*)d_in[5];
    float* out = (float*)d_out;

    int N = in_sizes[0] / DIN;
    int E = in_sizes[1] / 2;
    const int* esrc = ei;
    const int* edst = ei + E;

    // workspace layout (PAD chosen to fit: padded counters kill same-line atomic serialization)
    size_t fixed = (size_t)N * 128 * 4 * 2        // S + H1
                 + (size_t)N * 4                  // dinv
                 + (size_t)(N + 1) * 4            // rowstart
                 + (size_t)E * 4 * 2              // adj + rank
                 + 1024 * 4 + 8 * 256;            // bsum + align slack
    int PAD = (fixed + (size_t)N * 16 * 4 <= ws_size) ? 16 : 1;

    char* wsb = (char*)d_ws;
    size_t off = 0;
    auto alloc = [&](size_t bytes) {
        void* p = wsb + off;
        off = (off + bytes + 255) & ~(size_t)255;
        return p;
    };
    float* S        = (float*)alloc((size_t)N * 128 * 4);
    float* H1       = (float*)alloc((size_t)N * 128 * 4);
    float* dinv     = (float*)alloc((size_t)N * 4);
    int*   rowstart = (int*)alloc((size_t)(N + 1) * 4);
    int*   adj      = (int*)alloc((size_t)E * 4);
    int*   rank     = (int*)alloc((size_t)E * 4);
    int*   cnt      = (int*)alloc((size_t)N * PAD * 4);
    int*   bsum     = (int*)alloc(1024 * 4);

    int eb = (E + 255) / 256;
    int nb = (N + 255) / 256;
    int sb = (N + 1023) / 1024;

    hipMemsetAsync(cnt, 0, (size_t)N * PAD * 4, stream);
    k_count_rank<<<eb, 256, 0, stream>>>(edst, cnt, rank, E, PAD);
    k_dinv<<<nb, 256, 0, stream>>>(cnt, dinv, N, PAD);
    k_scan_partial<<<sb, 256, 0, stream>>>(cnt, rowstart, bsum, N, PAD);
    k_scan_bsum<<<1, 256, 0, stream>>>(bsum, sb);
    k_finalize<<<nb, 256, 0, stream>>>(rowstart, bsum, N, E);
    k_fill2<<<eb, 256, 0, stream>>>(esrc, edst, rank, rowstart, adj, E);

    dim3 g1((N + 31) / 32, DH / 64);
    k_gemm_scaled<<<g1, 256, 0, stream>>>(x, W1, dinv, S, N, DH);
    int ab = (N + 3) / 4;
    k_agg128<true><<<ab, 256, 0, stream>>>(S, rowstart, adj, dinv, b1, H1, N);

    dim3 g2((N + 31) / 32, DOUT / 64);
    k_gemm_scaled<<<g2, 256, 0, stream>>>(H1, W2, dinv, S, N, DOUT);
    k_agg64<<<ab, 256, 0, stream>>>(S, rowstart, adj, dinv, b2, out, N);
}

// Round 4
// 309.399 us; speedup vs baseline: 1.7141x; 1.1943x over previous
//
#include <hip/hip_runtime.h>

#define DIN 128
#define DH  128
#define DOUT 64

// ---------------- helpers ----------------

__device__ inline unsigned bf16rne(float f) {           // fp32 -> bf16 bits, round-nearest-even
    unsigned u = __float_as_uint(f);
    return (u + 0x7fffu + ((u >> 16) & 1u)) >> 16;
}

__device__ inline void acc8(float* a, uint4 v) {        // accumulate 8 bf16 (packed) into fp32
    a[0] += __uint_as_float(v.x << 16); a[1] += __uint_as_float(v.x & 0xffff0000u);
    a[2] += __uint_as_float(v.y << 16); a[3] += __uint_as_float(v.y & 0xffff0000u);
    a[4] += __uint_as_float(v.z << 16); a[5] += __uint_as_float(v.z & 0xffff0000u);
    a[6] += __uint_as_float(v.w << 16); a[7] += __uint_as_float(v.w & 0xffff0000u);
}

// ---------------- CSR build: one atomic pass (rank), atomic-free placement ----------------

__global__ void k_count_rank(const int* __restrict__ dst, int* __restrict__ cnt,
                             int* __restrict__ rank, int E, int pad) {
    int e = blockIdx.x * 256 + threadIdx.x;
    if (e < E) rank[e] = atomicAdd(&cnt[dst[e] * pad], 1);
}

__global__ void k_dinv(const int* __restrict__ cnt, float* __restrict__ dinv, int n, int pad) {
    int i = blockIdx.x * 256 + threadIdx.x;
    if (i < n) dinv[i] = rsqrtf((float)(cnt[i * pad] + 1));
}

__global__ void k_scan_partial(const int* __restrict__ cnt, int* __restrict__ excl,
                               int* __restrict__ bsum, int n, int pad) {
    __shared__ int sd[256];
    int t = threadIdx.x;
    int base = blockIdx.x * 1024 + t * 4;
    int v0 = (base + 0 < n) ? cnt[(base + 0) * pad] : 0;
    int v1 = (base + 1 < n) ? cnt[(base + 1) * pad] : 0;
    int v2 = (base + 2 < n) ? cnt[(base + 2) * pad] : 0;
    int v3 = (base + 3 < n) ? cnt[(base + 3) * pad] : 0;
    int s = v0 + v1 + v2 + v3;
    sd[t] = s;
    __syncthreads();
    for (int off = 1; off < 256; off <<= 1) {
        int x = (t >= off) ? sd[t - off] : 0;
        __syncthreads();
        sd[t] += x;
        __syncthreads();
    }
    int incl = sd[t];
    if (t == 255) bsum[blockIdx.x] = incl;
    int run = incl - s;
    if (base + 0 < n) excl[base + 0] = run;  run += v0;
    if (base + 1 < n) excl[base + 1] = run;  run += v1;
    if (base + 2 < n) excl[base + 2] = run;  run += v2;
    if (base + 3 < n) excl[base + 3] = run;
}

__global__ void k_scan_bsum(int* __restrict__ bsum, int nb) {
    __shared__ int sd[256];
    int t = threadIdx.x;
    int v = (t < nb) ? bsum[t] : 0;
    sd[t] = v;
    __syncthreads();
    for (int off = 1; off < 256; off <<= 1) {
        int x = (t >= off) ? sd[t - off] : 0;
        __syncthreads();
        sd[t] += x;
        __syncthreads();
    }
    if (t < nb) bsum[t] = sd[t] - v;
}

__global__ void k_finalize(int* __restrict__ rowstart, const int* __restrict__ bsum,
                           int n, int E) {
    int i = blockIdx.x * 256 + threadIdx.x;
    if (i < n) rowstart[i] += bsum[i >> 10];
    if (i == 0) rowstart[n] = E;
}

__global__ void k_fill2(const int* __restrict__ src, const int* __restrict__ dst,
                        const int* __restrict__ rank, const int* __restrict__ rowstart,
                        int* __restrict__ adj, int E) {
    int e = blockIdx.x * 256 + threadIdx.x;
    if (e < E) adj[rowstart[dst[e]] + rank[e]] = src[e];
}

// ---------------- GEMM: S[i][j] = bf16( dinv[i] * sum_k A[i][k] * W[k][j] ) ----------------

__global__ void k_gemm_scaled(const float* __restrict__ A, const float* __restrict__ W,
                              const float* __restrict__ dinv, unsigned short* __restrict__ S,
                              int M, int ncols) {
    __shared__ float xs[32 * 132];
    __shared__ float ws[128 * 64];
    int tid = threadIdx.x;
    int row0 = blockIdx.x * 32;
    int j0   = blockIdx.y * 64;

    #pragma unroll
    for (int i = 0; i < 4; i++) {
        int idx = tid + 256 * i;
        int r = idx >> 5;
        int kq = idx & 31;
        float4 val = make_float4(0.f, 0.f, 0.f, 0.f);
        int row = row0 + r;
        if (row < M) val = *(const float4*)(A + (size_t)row * 128 + kq * 4);
        *(float4*)(xs + r * 132 + kq * 4) = val;
    }
    #pragma unroll
    for (int i = 0; i < 8; i++) {
        int idx = tid + 256 * i;
        int k = idx >> 4;
        int jq = idx & 15;
        float4 val = *(const float4*)(W + (size_t)k * ncols + j0 + jq * 4);
        *(float4*)(ws + k * 64 + jq * 4) = val;
    }
    __syncthreads();

    int tx = tid & 15;
    int ty = tid >> 4;
    float acc[2][4] = {};
    #pragma unroll 8
    for (int k = 0; k < 128; k++) {
        float4 b = *(const float4*)(ws + k * 64 + tx * 4);
        float a0 = xs[(ty * 2 + 0) * 132 + k];
        float a1 = xs[(ty * 2 + 1) * 132 + k];
        acc[0][0] += a0 * b.x; acc[0][1] += a0 * b.y; acc[0][2] += a0 * b.z; acc[0][3] += a0 * b.w;
        acc[1][0] += a1 * b.x; acc[1][1] += a1 * b.y; acc[1][2] += a1 * b.z; acc[1][3] += a1 * b.w;
    }

    #pragma unroll
    for (int r = 0; r < 2; r++) {
        int row = row0 + ty * 2 + r;
        if (row < M) {
            float dv = dinv[row];
            uint2 o;
            o.x = bf16rne(dv * acc[r][0]) | (bf16rne(dv * acc[r][1]) << 16);
            o.y = bf16rne(dv * acc[r][2]) | (bf16rne(dv * acc[r][3]) << 16);
            *(uint2*)(S + (size_t)row * ncols + j0 + tx * 4) = o;
        }
    }
}

// ---------------- Aggregation: bf16 S, packed multi-edge uint4 gathers ----------------
// D=128: row = 256B; 16 lanes/row -> 4 edges per load, 4 loads in flight (16 edges/iter).
// D=64 : row = 128B;  8 lanes/row -> 8 edges per load, 4 loads in flight (32 edges/iter).

template <bool RELU>
__global__ void k_agg128(const unsigned short* __restrict__ S, const int* __restrict__ rowstart,
                         const int* __restrict__ adj, const float* __restrict__ dinv,
                         const float* __restrict__ bias, float* __restrict__ out, int n) {
    int wave = threadIdx.x >> 6;
    int lane = threadIdx.x & 63;
    int node = blockIdx.x * 4 + wave;
    if (node >= n) return;
    int start = rowstart[node];
    int end   = rowstart[node + 1];
    int g  = lane >> 4;        // edge slot within a quad
    int fo = lane & 15;        // uint4 slot within the 256B row

    const uint4* S4 = (const uint4*)S;   // 16 uint4 per row
    float a0[8] = {}, a1[8] = {};

    while (start < end) {
        int cnt = end - start;
        if (cnt > 64) cnt = 64;
        int nb = adj[start + (lane < cnt ? lane : cnt - 1)];
        int t = 0;
        for (; t + 16 <= cnt; t += 16) {
            int jA = __shfl(nb, t + 0  + g);
            int jB = __shfl(nb, t + 4  + g);
            int jC = __shfl(nb, t + 8  + g);
            int jD = __shfl(nb, t + 12 + g);
            uint4 mA = S4[(size_t)jA * 16 + fo];
            uint4 mB = S4[(size_t)jB * 16 + fo];
            uint4 mC = S4[(size_t)jC * 16 + fo];
            uint4 mD = S4[(size_t)jD * 16 + fo];
            acc8(a0, mA); acc8(a1, mB); acc8(a0, mC); acc8(a1, mD);
        }
        for (; t + 4 <= cnt; t += 4) {
            int j = __shfl(nb, t + g);
            uint4 m = S4[(size_t)j * 16 + fo];
            acc8(a0, m);
        }
        if (t < cnt) {                       // 1..3 leftover edges
            int i1 = t + g;
            int j = __shfl(nb, i1 < cnt ? i1 : cnt - 1);
            uint4 m = S4[(size_t)j * 16 + fo];
            if (i1 < cnt) acc8(a1, m);
        }
        start += 64;
    }

    float acc[8];
    #pragma unroll
    for (int i = 0; i < 8; i++) {
        float v = a0[i] + a1[i];
        v += __shfl_xor(v, 16);
        v += __shfl_xor(v, 32);
        acc[i] = v;
    }

    uint4 selfu = ((const uint4*)S)[(size_t)node * 16 + fo];
    float self[8] = {};
    acc8(self, selfu);
    float dv = dinv[node];
    float4 bb0 = ((const float4*)bias)[fo * 2 + 0];
    float4 bb1 = ((const float4*)bias)[fo * 2 + 1];
    float o[8];
    o[0] = dv * (acc[0] + self[0]) + bb0.x;
    o[1] = dv * (acc[1] + self[1]) + bb0.y;
    o[2] = dv * (acc[2] + self[2]) + bb0.z;
    o[3] = dv * (acc[3] + self[3]) + bb0.w;
    o[4] = dv * (acc[4] + self[4]) + bb1.x;
    o[5] = dv * (acc[5] + self[5]) + bb1.y;
    o[6] = dv * (acc[6] + self[6]) + bb1.z;
    o[7] = dv * (acc[7] + self[7]) + bb1.w;
    if (RELU) {
        #pragma unroll
        for (int i = 0; i < 8; i++) o[i] = fmaxf(o[i], 0.f);
    }
    if (g == 0) {
        float4* op = (float4*)(out + (size_t)node * 128 + fo * 8);
        op[0] = make_float4(o[0], o[1], o[2], o[3]);
        op[1] = make_float4(o[4], o[5], o[6], o[7]);
    }
}

__global__ void k_agg64(const unsigned short* __restrict__ S, const int* __restrict__ rowstart,
                        const int* __restrict__ adj, const float* __restrict__ dinv,
                        const float* __restrict__ bias, float* __restrict__ out, int n) {
    int wave = threadIdx.x >> 6;
    int lane = threadIdx.x & 63;
    int node = blockIdx.x * 4 + wave;
    if (node >= n) return;
    int start = rowstart[node];
    int end   = rowstart[node + 1];
    int g  = lane >> 3;        // edge slot within an octet
    int fo = lane & 7;         // uint4 slot within the 128B row

    const uint4* S4 = (const uint4*)S;   // 8 uint4 per row
    float a0[8] = {}, a1[8] = {};

    while (start < end) {
        int cnt = end - start;
        if (cnt > 64) cnt = 64;
        int nb = adj[start + (lane < cnt ? lane : cnt - 1)];
        int t = 0;
        for (; t + 32 <= cnt; t += 32) {
            int jA = __shfl(nb, t + 0  + g);
            int jB = __shfl(nb, t + 8  + g);
            int jC = __shfl(nb, t + 16 + g);
            int jD = __shfl(nb, t + 24 + g);
            uint4 mA = S4[(size_t)jA * 8 + fo];
            uint4 mB = S4[(size_t)jB * 8 + fo];
            uint4 mC = S4[(size_t)jC * 8 + fo];
            uint4 mD = S4[(size_t)jD * 8 + fo];
            acc8(a0, mA); acc8(a1, mB); acc8(a0, mC); acc8(a1, mD);
        }
        for (; t + 8 <= cnt; t += 8) {
            int j = __shfl(nb, t + g);
            uint4 m = S4[(size_t)j * 8 + fo];
            acc8(a0, m);
        }
        if (t < cnt) {                       // 1..7 leftover edges
            int i1 = t + g;
            int j = __shfl(nb, i1 < cnt ? i1 : cnt - 1);
            uint4 m = S4[(size_t)j * 8 + fo];
            if (i1 < cnt) acc8(a1, m);
        }
        start += 64;
    }

    float acc[8];
    #pragma unroll
    for (int i = 0; i < 8; i++) {
        float v = a0[i] + a1[i];
        v += __shfl_xor(v, 8);
        v += __shfl_xor(v, 16);
        v += __shfl_xor(v, 32);
        acc[i] = v;
    }

    uint4 selfu = ((const uint4*)S)[(size_t)node * 8 + fo];
    float self[8] = {};
    acc8(self, selfu);
    float dv = dinv[node];
    float4 bb0 = ((const float4*)bias)[fo * 2 + 0];
    float4 bb1 = ((const float4*)bias)[fo * 2 + 1];
    float o[8];
    o[0] = dv * (acc[0] + self[0]) + bb0.x;
    o[1] = dv * (acc[1] + self[1]) + bb0.y;
    o[2] = dv * (acc[2] + self[2]) + bb0.z;
    o[3] = dv * (acc[3] + self[3]) + bb0.w;
    o[4] = dv * (acc[4] + self[4]) + bb1.x;
    o[5] = dv * (acc[5] + self[5]) + bb1.y;
    o[6] = dv * (acc[6] + self[6]) + bb1.z;
    o[7] = dv * (acc[7] + self[7]) + bb1.w;
    if (g == 0) {
        float4* op = (float4*)(out + (size_t)node * 64 + fo * 8);
        op[0] = make_float4(o[0], o[1], o[2], o[3]);
        op[1] = make_float4(o[4], o[5], o[6], o[7]);
    }
}

// ---------------- launch ----------------

extern "C" void kernel_launch(void* const* d_in, const int* in_sizes, int n_in,
                              void* d_out, int out_size, void* d_ws, size_t ws_size,
                              hipStream_t stream) {
    const float* x  = (const float*)d_in[0];
    const int*   ei = (const int*)d_in[1];
    const float* W1 = (const float*)d_in[2];
    const float* b1 = (const float*)d_in[3];
    const float* W2 = (const float*)d_in[4];
    const float* b2 = (const float*)d_in[5];
    float* out = (float*)d_out;

    int N = in_sizes[0] / DIN;
    int E = in_sizes[1] / 2;
    const int* esrc = ei;
    const int* edst = ei + E;

    size_t fixed = (size_t)N * 128 * 2        // S (bf16)
                 + (size_t)N * 128 * 4        // H1 (fp32)
                 + (size_t)N * 4              // dinv
                 + (size_t)(N + 1) * 4        // rowstart
                 + (size_t)E * 4 * 2          // adj + rank
                 + 1024 * 4 + 8 * 256;
    int PAD = (fixed + (size_t)N * 16 * 4 <= ws_size) ? 16 : 1;

    char* wsb = (char*)d_ws;
    size_t off = 0;
    auto alloc = [&](size_t bytes) {
        void* p = wsb + off;
        off = (off + bytes + 255) & ~(size_t)255;
        return p;
    };
    unsigned short* S = (unsigned short*)alloc((size_t)N * 128 * 2);   // bf16, reused by layer 2
    float* H1       = (float*)alloc((size_t)N * 128 * 4);
    float* dinv     = (float*)alloc((size_t)N * 4);
    int*   rowstart = (int*)alloc((size_t)(N + 1) * 4);
    int*   adj      = (int*)alloc((size_t)E * 4);
    int*   rank     = (int*)alloc((size_t)E * 4);
    int*   cnt      = (int*)alloc((size_t)N * PAD * 4);
    int*   bsum     = (int*)alloc(1024 * 4);

    int eb = (E + 255) / 256;
    int nb = (N + 255) / 256;
    int sb = (N + 1023) / 1024;

    hipMemsetAsync(cnt, 0, (size_t)N * PAD * 4, stream);
    k_count_rank<<<eb, 256, 0, stream>>>(edst, cnt, rank, E, PAD);
    k_dinv<<<nb, 256, 0, stream>>>(cnt, dinv, N, PAD);
    k_scan_partial<<<sb, 256, 0, stream>>>(cnt, rowstart, bsum, N, PAD);
    k_scan_bsum<<<1, 256, 0, stream>>>(bsum, sb);
    k_finalize<<<nb, 256, 0, stream>>>(rowstart, bsum, N, E);
    k_fill2<<<eb, 256, 0, stream>>>(esrc, edst, rank, rowstart, adj, E);

    dim3 g1((N + 31) / 32, DH / 64);
    k_gemm_scaled<<<g1, 256, 0, stream>>>(x, W1, dinv, S, N, DH);
    int ab = (N + 3) / 4;
    k_agg128<true><<<ab, 256, 0, stream>>>(S, rowstart, adj, dinv, b1, H1, N);

    dim3 g2((N + 31) / 32, DOUT / 64);
    k_gemm_scaled<<<g2, 256, 0, stream>>>(H1, W2, dinv, S, N, DOUT);
    k_agg64<<<ab, 256, 0, stream>>>(S, rowstart, adj, dinv, b2, out, N);
}